// Round 5
// baseline (108.473 us; speedup 1.0000x reference)
//
#include <hip/hip_runtime.h>
#include <hip/hip_bf16.h>

#define BDIM 8192
#define DDIM 256

typedef __attribute__((ext_vector_type(8))) short  s16x8;   // 8 x bf16 (4 VGPRs)
typedef __attribute__((ext_vector_type(4))) float  f32x4;   // MFMA accumulator

__device__ inline ushort f2bf(float x) {
    __hip_bfloat16 h = __float2bfloat16(x);
    ushort u;
    __builtin_memcpy(&u, &h, 2);
    return u;
}

// ---------------------------------------------------------------------------
// Kernel A: per-row stats + fragment-swizzled bf16 a_hat.
//   chunk_idx(row, k) = ((row>>4)*8 + k32)*64 + kg*16 + (row&15),
//   k32 = k/32, kg = (k/8)&3. A fragment load in cos_mse reads chunks
//   [base .. base+63] with chunk = base + lane -> contiguous 1KB.
// ---------------------------------------------------------------------------
__global__ __launch_bounds__(256) void row_stats(
    const float* __restrict__ A, const float* __restrict__ P,
    const float* __restrict__ N, ushort* __restrict__ Asw,
    float* __restrict__ partial_trip)
{
    __shared__ float tsh[4];
    const int wave = threadIdx.x >> 6;
    const int lane = threadIdx.x & 63;
    const int row  = blockIdx.x * 4 + wave;

    const float4 a = *(reinterpret_cast<const float4*>(A + (size_t)row * DDIM) + lane);
    const float4 p = *(reinterpret_cast<const float4*>(P + (size_t)row * DDIM) + lane);
    const float4 n = *(reinterpret_cast<const float4*>(N + (size_t)row * DDIM) + lane);

    float sa = a.x*a.x + a.y*a.y + a.z*a.z + a.w*a.w;

    float d0 = a.x - p.x + 1e-6f, d1 = a.y - p.y + 1e-6f;
    float d2 = a.z - p.z + 1e-6f, d3 = a.w - p.w + 1e-6f;
    float sp = d0*d0 + d1*d1 + d2*d2 + d3*d3;

    d0 = a.x - n.x + 1e-6f; d1 = a.y - n.y + 1e-6f;
    d2 = a.z - n.z + 1e-6f; d3 = a.w - n.w + 1e-6f;
    float sn = d0*d0 + d1*d1 + d2*d2 + d3*d3;

    #pragma unroll
    for (int off = 32; off > 0; off >>= 1) {
        sa += __shfl_xor(sa, off);
        sp += __shfl_xor(sp, off);
        sn += __shfl_xor(sn, off);
    }

    const float inv = 1.0f / fmaxf(sqrtf(sa), 1e-8f);

    ushort4 hv;
    hv.x = f2bf(a.x * inv);
    hv.y = f2bf(a.y * inv);
    hv.z = f2bf(a.z * inv);
    hv.w = f2bf(a.w * inv);
    const size_t chunk = ((size_t)(row >> 4) * 8 + (lane >> 3)) * 64
                       + (size_t)(((lane >> 1) & 3) * 16 + (row & 15));
    *reinterpret_cast<ushort4*>(Asw + chunk * 8 + (lane & 1) * 4) = hv;

    if (lane == 0)
        tsh[wave] = fmaxf(sqrtf(sp) - sqrtf(sn) + 0.2f, 0.0f);
    __syncthreads();
    if (threadIdx.x == 0)
        partial_trip[blockIdx.x] = tsh[0] + tsh[1] + tsh[2] + tsh[3];
}

// ---------------------------------------------------------------------------
// Kernel B (persistent, barrier-free): 512 blocks (2/CU), 8 tiles of 128x128
// each, constant ti per block (A-panel L1/L2-hot). Per tile:
//   1. K-loop: A/B fragments from L2 (swizzled a_hat) + MFMA. No HBM loads
//      precede these, so fragment waits never drain an HBM stream (vmcnt is
//      in-order!).
//   2. sched_barrier, then 64 S dwords per lane loaded DIRECTLY INTO
//      REGISTERS in MFMA C-fragment layout (16-lane x 64B segments,
//      nontemporal: S must not evict a_hat from L2).
//   3. Consume: local += (acc - S)^2. Waits here stall while HBM streams --
//      roofline behavior. No __syncthreads anywhere; 8 free-running waves/CU
//      keep HBM saturated.
// ---------------------------------------------------------------------------
__global__ __launch_bounds__(256, 2) void cos_mse(
    const ushort* __restrict__ Asw,
    const float* __restrict__ S,
    float* __restrict__ partial_sim)
{
    const int tid  = threadIdx.x;
    const int w    = tid >> 6;
    const int lane = tid & 63;

    const int b   = blockIdx.x;           // 0..511
    const int xcd = b & 7;
    const int q   = b >> 3;               // 0..63
    const int ti  = (xcd * 8 + (q >> 3)) * 128;   // constant per block

    const int wr = (w >> 1) * 64;
    const int wc = (w & 1) * 64;
    const int fr = lane & 15;
    const int kg = lane >> 4;

    const ushort* ab = Asw + (size_t)((ti + wr) >> 4) * 4096 + (size_t)lane * 8;

    float local = 0.0f;

    for (int i = 0; i < 8; ++i) {
        const int tj = ((q & 7) * 8 + i) * 128;
        const ushort* bb = Asw + (size_t)((tj + wc) >> 4) * 4096 + (size_t)lane * 8;

        // ---- phase 1: MFMA, fragments from L2 only
        f32x4 acc[4][4] = {};
        #pragma unroll 2
        for (int k32 = 0; k32 < 8; ++k32) {
            s16x8 afr[4], bfr[4];
            #pragma unroll
            for (int m = 0; m < 4; ++m)
                afr[m] = *reinterpret_cast<const s16x8*>(
                    ab + (size_t)m * 4096 + k32 * 512);
            #pragma unroll
            for (int n = 0; n < 4; ++n)
                bfr[n] = *reinterpret_cast<const s16x8*>(
                    bb + (size_t)n * 4096 + k32 * 512);
            #pragma unroll
            for (int m = 0; m < 4; ++m)
                #pragma unroll
                for (int n = 0; n < 4; ++n)
                    acc[m][n] = __builtin_amdgcn_mfma_f32_16x16x32_bf16(
                        afr[m], bfr[n], acc[m][n], 0, 0, 0);
        }

        // keep the HBM S-loads strictly AFTER the L2 fragment loads
        __builtin_amdgcn_sched_barrier(0);

        // ---- phase 2: S directly to registers in C-fragment layout
        // row = ti+wr + m*16 + kg*4 + reg ; col = tj+wc + n*16 + fr
        const float* sbase = S + (size_t)(ti + wr + kg * 4) * BDIM + tj + wc + fr;
        float sv[4][4][4];
        #pragma unroll
        for (int m = 0; m < 4; ++m)
            #pragma unroll
            for (int reg = 0; reg < 4; ++reg)
                #pragma unroll
                for (int n = 0; n < 4; ++n)
                    sv[m][reg][n] = __builtin_nontemporal_load(
                        sbase + (size_t)(m * 16 + reg) * BDIM + n * 16);

        __builtin_amdgcn_sched_barrier(0);

        // ---- phase 3: fused (cos - S)^2
        #pragma unroll
        for (int m = 0; m < 4; ++m)
            #pragma unroll
            for (int reg = 0; reg < 4; ++reg)
                #pragma unroll
                for (int n = 0; n < 4; ++n) {
                    const float d = acc[m][n][reg] - sv[m][reg][n];
                    local += d * d;
                }
    }

    #pragma unroll
    for (int off = 32; off > 0; off >>= 1)
        local += __shfl_down(local, off);
    if (lane == 0)
        partial_sim[b * 4 + w] = local;
}

// ---------------------------------------------------------------------------
// finalize: out = sum(partial_trip)/B + sum(partial_sim)/B^2
// ---------------------------------------------------------------------------
__global__ __launch_bounds__(256) void finalize(
    const float* __restrict__ pt, const float* __restrict__ ps,
    float* __restrict__ out)
{
    __shared__ float sh[4];
    float v = 0.0f;
    for (int i = threadIdx.x; i < 2048; i += 256)
        v += pt[i] * (1.0f / (float)BDIM);
    for (int i = threadIdx.x; i < 2048; i += 256)
        v += ps[i] * (1.0f / ((float)BDIM * (float)BDIM));
    #pragma unroll
    for (int off = 32; off > 0; off >>= 1) v += __shfl_down(v, off);
    const int w = threadIdx.x >> 6, lane = threadIdx.x & 63;
    if (lane == 0) sh[w] = v;
    __syncthreads();
    if (threadIdx.x == 0) out[0] = sh[0] + sh[1] + sh[2] + sh[3];
}

extern "C" void kernel_launch(void* const* d_in, const int* in_sizes, int n_in,
                              void* d_out, int out_size, void* d_ws, size_t ws_size,
                              hipStream_t stream)
{
    const float* anchor   = (const float*)d_in[0];
    const float* positive = (const float*)d_in[1];
    const float* negative = (const float*)d_in[2];
    const float* S        = (const float*)d_in[3];
    float* out = (float*)d_out;

    float*  partial_trip = (float*)d_ws;                        // 2048 floats
    float*  partial_sim  = (float*)((char*)d_ws + 8192);        // 2048 floats
    ushort* Asw          = (ushort*)((char*)d_ws + 32768);      // 4 MB swizzled a_hat

    row_stats<<<BDIM / 4, 256, 0, stream>>>(anchor, positive, negative, Asw, partial_trip);
    cos_mse<<<512, 256, 0, stream>>>(Asw, S, partial_sim);
    finalize<<<1, 256, 0, stream>>>(partial_trip, partial_sim, out);
}